// Round 7
// baseline (223.359 us; speedup 1.0000x reference)
//
#include <hip/hip_runtime.h>

// Problem constants
#define BB 256
#define NN 5
#define CHW 64000            // C*H*W floats per (b,n)
#define EPSF 1e-8f
#define TPB 1024
#define JBLK 8               // blocks cooperating on one b
#define CHB 80               // channels per block (4 oc-groups of 20)
#define CELLS 100            // 4 oc * 25 pooled cells per block

typedef float f4 __attribute__((ext_vector_type(4)));

// One-read cooperative kernel. grid = 256 (1 block/CU, all resident).
// Set s = blocks [8s, 8s+8) cooperate on b = it*32 + s, it = 0..7.
// Block j of a set owns channels [80j, 80j+80) of all 5 shots:
//   Phase A: stage 160,000 B chunk -> LDS (the ONLY global read of x).
//   Pool:    125 cells x 5 shots locally; partial dot/na2/nb2 (11 floats).
//   Sync:    device-scope partial write + release counter; spin-acquire to 8.
//   Phase C: out chunk = sum_n sim[n] * xl[n] from LDS; NT store.
__global__ __launch_bounds__(TPB, 4) void k_coop(const float* __restrict__ x,
                                                 float* __restrict__ out,
                                                 float* __restrict__ g_part, // [BB][JBLK][11]
                                                 int* __restrict__ g_cnt) {  // [BB]
    __shared__ float xl[NN * CHB * 100];   // 160,000 B
    __shared__ float feats_l[CELLS][6];    // pooled cells x shots (padded)
    __shared__ float red[2][11];
    __shared__ float s_sim[NN];
    const int tid = threadIdx.x;
    const int set = blockIdx.x >> 3;
    const int j   = blockIdx.x & 7;

    for (int it = 0; it < BB / 32; ++it) {
        const int b = it * 32 + set;

        // ---------- Phase A: stage chunk to LDS (coalesced f4) ----------
        const f4* __restrict__ xg = reinterpret_cast<const f4*>(x);
        #pragma unroll
        for (int n = 0; n < NN; ++n) {
            const f4* __restrict__ src = xg + ((size_t)(b * NN + n) * 640 + (size_t)CHB * j) * 25;
            f4* __restrict__ dst = reinterpret_cast<f4*>(xl + n * (CHB * 100));
            for (int i = tid; i < CHB * 25; i += TPB)   // 2000 f4
                dst[i] = src[i];
        }
        __syncthreads();

        // ---------- Pool: 500 threads, one (n, cell) each ----------
        if (tid < NN * CELLS) {
            const int n    = tid / CELLS;
            const int cell = tid - n * CELLS;       // ocl*25 + oh*5 + ow
            const int ocl  = cell / 25;
            const int c25  = cell - ocl * 25;
            const int oh   = c25 / 5;
            const int ow   = c25 - oh * 5;
            const float* __restrict__ bp =
                xl + n * (CHB * 100) + (ocl * 20) * 100 + oh * 20 + ow * 2;
            float s = 0.f;
            #pragma unroll
            for (int cc = 0; cc < 20; ++cc) {
                const float* q = bp + cc * 100;
                s += (q[0] + q[1]) + (q[10] + q[11]);
            }
            feats_l[cell][n] = s * (1.f / 80.f);
        }
        __syncthreads();

        // ---------- Local partials: 100 cell-threads, reduce in waves 0,1 ----
        float part[11];
        #pragma unroll
        for (int k = 0; k < 11; ++k) part[k] = 0.f;
        if (tid < CELLS) {
            float f[NN], p = 0.f;
            #pragma unroll
            for (int n = 0; n < NN; ++n) { f[n] = feats_l[tid][n]; p += f[n]; }
            #pragma unroll
            for (int n = 0; n < NN; ++n) { part[n] = f[n] * p; part[5 + n] = f[n] * f[n]; }
            part[10] = p * p;
        }
        if (tid < 128) {
            #pragma unroll
            for (int off = 32; off >= 1; off >>= 1) {
                #pragma unroll
                for (int k = 0; k < 11; ++k)
                    part[k] += __shfl_down(part[k], off, 64);
            }
            if ((tid & 63) == 0) {
                #pragma unroll
                for (int k = 0; k < 11; ++k) red[tid >> 6][k] = part[k];
            }
        }
        __syncthreads();

        // ---------- Cross-block exchange (thread 0) ----------
        if (tid == 0) {
            #pragma unroll
            for (int k = 0; k < 11; ++k) {
                const float v = red[0][k] + red[1][k];
                __hip_atomic_store(&g_part[(b * JBLK + j) * 11 + k], v,
                                   __ATOMIC_RELAXED, __HIP_MEMORY_SCOPE_AGENT);
            }
            __hip_atomic_fetch_add(&g_cnt[b], 1,
                                   __ATOMIC_RELEASE, __HIP_MEMORY_SCOPE_AGENT);
            while (__hip_atomic_load(&g_cnt[b],
                                     __ATOMIC_ACQUIRE, __HIP_MEMORY_SCOPE_AGENT) < JBLK)
                __builtin_amdgcn_s_sleep(16);
            float tot[11];
            #pragma unroll
            for (int k = 0; k < 11; ++k) tot[k] = 0.f;
            for (int jj = 0; jj < JBLK; ++jj) {
                #pragma unroll
                for (int k = 0; k < 11; ++k)
                    tot[k] += __hip_atomic_load(&g_part[(b * JBLK + jj) * 11 + k],
                                                __ATOMIC_RELAXED, __HIP_MEMORY_SCOPE_AGENT);
            }
            const float nb = sqrtf(tot[10]);
            #pragma unroll
            for (int n = 0; n < NN; ++n)
                s_sim[n] = tot[n] / fmaxf(sqrtf(tot[5 + n]) * nb, EPSF);
        }
        __syncthreads();

        // ---------- Phase C: out chunk from LDS, NT store ----------
        const float w0 = s_sim[0];
        const float w1 = s_sim[1];
        const float w2 = s_sim[2];
        const float w3 = s_sim[3];
        const float w4 = s_sim[4];
        const f4* __restrict__ xl4 = reinterpret_cast<const f4*>(xl);
        f4* __restrict__ og = reinterpret_cast<f4*>(out) +
                              ((size_t)b * 640 + (size_t)CHB * j) * 25;
        for (int i = tid; i < CHB * 25; i += TPB) {     // 2000 f4
            f4 o = w0 * xl4[i]
                 + w1 * xl4[i + 2000]
                 + w2 * xl4[i + 4000]
                 + w3 * xl4[i + 6000]
                 + w4 * xl4[i + 8000];
            __builtin_nontemporal_store(o, og + i);
        }
        __syncthreads();   // protect xl before next iteration's overwrite
    }
}

extern "C" void kernel_launch(void* const* d_in, const int* in_sizes, int n_in,
                              void* d_out, int out_size, void* d_ws, size_t ws_size,
                              hipStream_t stream) {
    const float* x = (const float*)d_in[0];
    float* out = (float*)d_out;
    // ws layout: g_cnt [256 ints] | g_part [256*8*11 floats]
    int* g_cnt = (int*)d_ws;
    float* g_part = (float*)((char*)d_ws + 1024);
    // Zero counters + partials each call (capture-safe, deterministic replay).
    hipMemsetAsync(d_ws, 0, 1024 + (size_t)BB * JBLK * 11 * sizeof(float), stream);
    k_coop<<<BB, TPB, 0, stream>>>(x, out, g_part, g_cnt);
}